// Round 1
// baseline (1580.996 us; speedup 1.0000x reference)
//
#include <hip/hip_runtime.h>
#include <hip/hip_bf16.h>
#include <math.h>

// ---------------------------------------------------------------------------
// GNN: node_rep = attr @ W_inp^T + b
//      2x { att = segment_softmax(log(adv)); aggr = scatter(att*rep[src], dst);
//           rep = LN(gelu((aggr+rep) @ W_a^T + b)) }
//      out = rep @ W_out^T + b_out
// segment_softmax(log a) == a / (sum_seg a + amax*1e-16)  -> per-node scalar,
// applied post-aggregation. CSR (by dst) built on device each call.
// ---------------------------------------------------------------------------

#define WAVE 64

__global__ void k_count(const int* __restrict__ dst, int E, int* __restrict__ deg) {
    int e = blockIdx.x * blockDim.x + threadIdx.x;
    if (e < E) atomicAdd(&deg[dst[e]], 1);
}

__global__ __launch_bounds__(1024) void k_scan(const int* __restrict__ deg, int n,
                                               int* __restrict__ row_ptr,
                                               int* __restrict__ cursor) {
    __shared__ int sd[1024];
    int t = threadIdx.x;
    int C = (n + 1023) >> 10;
    int base = t * C;
    int lim = min(base + C, n);
    int lsum = 0;
    for (int i = base; i < lim; ++i) lsum += deg[i];
    sd[t] = lsum;
    __syncthreads();
    for (int off = 1; off < 1024; off <<= 1) {
        int v = (t >= off) ? sd[t - off] : 0;
        __syncthreads();
        sd[t] += v;
        __syncthreads();
    }
    int excl = sd[t] - lsum;
    if (t == 0) row_ptr[n] = sd[1023];
    int run = excl;
    for (int i = base; i < lim; ++i) {
        row_ptr[i] = run;
        cursor[i] = run;
        run += deg[i];
    }
}

__global__ void k_scatter(const int* __restrict__ src, const int* __restrict__ dst,
                          const float* __restrict__ adv, int E,
                          int* __restrict__ cursor,
                          int2* __restrict__ pair0, int2* __restrict__ pair1) {
    int e = blockIdx.x * blockDim.x + threadIdx.x;
    if (e < E) {
        int d = dst[e];
        int p = atomicAdd(&cursor[d], 1);
        int s = src[e];
        pair0[p] = make_int2(s, __float_as_int(adv[e]));
        pair1[p] = make_int2(s, __float_as_int(adv[E + e]));
    }
}

// rep_out[node][o] = sum_k attr[node][k] * W[o][k] + b[o]
__global__ __launch_bounds__(256) void k_input(const float* __restrict__ attr,
                                               const float* __restrict__ W,
                                               const float* __restrict__ b,
                                               float* __restrict__ out, int n) {
    __shared__ float Wt[128 * 129];  // Wt[k*129+o]
    __shared__ float xb[4][128];
    for (int idx = threadIdx.x; idx < 128 * 128; idx += 256) {
        int o = idx >> 7, k = idx & 127;
        Wt[k * 129 + o] = W[idx];
    }
    __syncthreads();
    int wave = threadIdx.x >> 6, lane = threadIdx.x & 63;
    int node = blockIdx.x * 4 + wave;
    if (node < n) {
        float2 v = *(const float2*)&attr[(size_t)node * 128 + lane * 2];
        xb[wave][lane * 2] = v.x;
        xb[wave][lane * 2 + 1] = v.y;
    }
    __syncthreads();
    if (node < n) {
        float a0 = 0.f, a1 = 0.f;
#pragma unroll 8
        for (int k = 0; k < 128; ++k) {
            float xk = xb[wave][k];
            a0 = fmaf(xk, Wt[k * 129 + lane], a0);
            a1 = fmaf(xk, Wt[k * 129 + 64 + lane], a1);
        }
        out[(size_t)node * 128 + lane] = a0 + b[lane];
        out[(size_t)node * 128 + 64 + lane] = a1 + b[64 + lane];
    }
}

// one wave per node: aggregate incoming edges, add self, GEMM, gelu, LN
__global__ __launch_bounds__(256) void k_layer(const float* __restrict__ rep_in,
                                               const int* __restrict__ row_ptr,
                                               const int2* __restrict__ pairs,
                                               const float* __restrict__ W,
                                               const float* __restrict__ b,
                                               const float* __restrict__ lw,
                                               const float* __restrict__ lb,
                                               float* __restrict__ rep_out, int n) {
    __shared__ float Wt[128 * 129];
    __shared__ float xb[4][128];
    for (int idx = threadIdx.x; idx < 128 * 128; idx += 256) {
        int o = idx >> 7, k = idx & 127;
        Wt[k * 129 + o] = W[idx];
    }
    __syncthreads();
    int wave = threadIdx.x >> 6, lane = threadIdx.x & 63;
    int node = blockIdx.x * 4 + wave;
    if (node < n) {
        int s0 = row_ptr[node], s1 = row_ptr[node + 1];
        // softmax denominator: att_e = a_e / (ssum + amax*1e-16)
        float amax = 0.f, ssum = 0.f;
        for (int s = s0 + lane; s < s1; s += WAVE) {
            float a = __int_as_float(pairs[s].y);
            amax = fmaxf(amax, a);
            ssum += a;
        }
        for (int m = 1; m < WAVE; m <<= 1) {
            amax = fmaxf(amax, __shfl_xor(amax, m));
            ssum += __shfl_xor(ssum, m);
        }
        float inv = (s1 > s0) ? 1.f / (ssum + amax * 1e-16f) : 0.f;
        // aggregate: whole wave walks this node's edge list, lanes cover channels
        float accx = 0.f, accy = 0.f;
        for (int s = s0; s < s1; ++s) {
            int2 p = pairs[s];  // broadcast load
            float a = __int_as_float(p.y);
            float2 r = *(const float2*)&rep_in[(size_t)p.x * 128 + lane * 2];
            accx = fmaf(a, r.x, accx);
            accy = fmaf(a, r.y, accy);
        }
        float2 mine = *(const float2*)&rep_in[(size_t)node * 128 + lane * 2];
        xb[wave][lane * 2] = accx * inv + mine.x;
        xb[wave][lane * 2 + 1] = accy * inv + mine.y;
    }
    __syncthreads();
    if (node < n) {
        float a0 = 0.f, a1 = 0.f;
#pragma unroll 8
        for (int k = 0; k < 128; ++k) {
            float xk = xb[wave][k];
            a0 = fmaf(xk, Wt[k * 129 + lane], a0);
            a1 = fmaf(xk, Wt[k * 129 + 64 + lane], a1);
        }
        a0 += b[lane];
        a1 += b[lane + 64];
        // exact gelu
        float g0 = 0.5f * a0 * (1.f + erff(a0 * 0.70710678118654752f));
        float g1 = 0.5f * a1 * (1.f + erff(a1 * 0.70710678118654752f));
        // layernorm across the 128 values (2 per lane)
        float sv = g0 + g1;
        for (int m = 1; m < WAVE; m <<= 1) sv += __shfl_xor(sv, m);
        float mu = sv * (1.f / 128.f);
        float d0 = g0 - mu, d1 = g1 - mu;
        float vv = d0 * d0 + d1 * d1;
        for (int m = 1; m < WAVE; m <<= 1) vv += __shfl_xor(vv, m);
        float rstd = rsqrtf(vv * (1.f / 128.f) + 1e-5f);
        rep_out[(size_t)node * 128 + lane] = d0 * rstd * lw[lane] + lb[lane];
        rep_out[(size_t)node * 128 + 64 + lane] = d1 * rstd * lw[lane + 64] + lb[lane + 64];
    }
}

// out[node][o] = sum_k rep[node][k] * W[o][k] + b[o], o in [0,64)
__global__ __launch_bounds__(256) void k_out(const float* __restrict__ rep,
                                             const float* __restrict__ W,
                                             const float* __restrict__ b,
                                             float* __restrict__ out, int n) {
    __shared__ float Wt[128 * 65];  // Wt[k*65+o]
    __shared__ float xb[4][128];
    for (int idx = threadIdx.x; idx < 64 * 128; idx += 256) {
        int o = idx >> 7, k = idx & 127;
        Wt[k * 65 + o] = W[idx];
    }
    __syncthreads();
    int wave = threadIdx.x >> 6, lane = threadIdx.x & 63;
    int node = blockIdx.x * 4 + wave;
    if (node < n) {
        float2 v = *(const float2*)&rep[(size_t)node * 128 + lane * 2];
        xb[wave][lane * 2] = v.x;
        xb[wave][lane * 2 + 1] = v.y;
    }
    __syncthreads();
    if (node < n) {
        float acc = 0.f;
#pragma unroll 8
        for (int k = 0; k < 128; ++k) acc = fmaf(xb[wave][k], Wt[k * 65 + lane], acc);
        out[(size_t)node * 64 + lane] = acc + b[lane];
    }
}

extern "C" void kernel_launch(void* const* d_in, const int* in_sizes, int n_in,
                              void* d_out, int out_size, void* d_ws, size_t ws_size,
                              hipStream_t stream) {
    const float* node_attr = (const float*)d_in[0];
    const int* ei = (const int*)d_in[1];
    // d_in[2] = batch_idx (unused)
    const float* adv = (const float*)d_in[3];
    const float* W_inp = (const float*)d_in[4];
    const float* b_inp = (const float*)d_in[5];
    const float* W_a = (const float*)d_in[6];
    const float* b_a = (const float*)d_in[7];
    const float* ln_w = (const float*)d_in[8];
    const float* ln_b = (const float*)d_in[9];
    const float* W_out = (const float*)d_in[10];
    const float* b_out = (const float*)d_in[11];

    const int n = in_sizes[0] / 128;
    const int E = in_sizes[1] / 2;
    const int H = 128;

    // workspace layout
    float* rep0 = (float*)d_ws;
    float* rep1 = rep0 + (size_t)n * H;
    int2* pair0 = (int2*)(rep1 + (size_t)n * H);
    int2* pair1 = pair0 + E;
    int* deg = (int*)(pair1 + E);
    int* cursor = deg + n;
    int* row_ptr = cursor + n;

    const int* src = ei;
    const int* dst = ei + E;

    hipMemsetAsync(deg, 0, (size_t)n * sizeof(int), stream);

    int eb = (E + 255) / 256;
    k_count<<<eb, 256, 0, stream>>>(dst, E, deg);
    k_scan<<<1, 1024, 0, stream>>>(deg, n, row_ptr, cursor);
    k_scatter<<<eb, 256, 0, stream>>>(src, dst, adv, E, cursor, pair0, pair1);

    int nb = (n + 3) / 4;
    k_input<<<nb, 256, 0, stream>>>(node_attr, W_inp, b_inp, rep0, n);
    k_layer<<<nb, 256, 0, stream>>>(rep0, row_ptr, pair0, W_a, b_a, ln_w, ln_b, rep1, n);
    k_layer<<<nb, 256, 0, stream>>>(rep1, row_ptr, pair1, W_a + 128 * 128, b_a + 128,
                                    ln_w + 128, ln_b + 128, rep0, n);
    k_out<<<nb, 256, 0, stream>>>(rep0, W_out, b_out, (float*)d_out, n);
}

// Round 2
// 822.805 us; speedup vs baseline: 1.9215x; 1.9215x over previous
//
#include <hip/hip_runtime.h>
#include <hip/hip_bf16.h>
#include <math.h>

// ---------------------------------------------------------------------------
// GNN: rep = attr @ W_inp^T + b
//      2x { x = (segsoftmax-weighted aggr of rep[src] by dst) + rep;
//           rep = LN(gelu(x @ W_a^T + b)) }
//      out = rep @ W_out^T + b_out
// segment_softmax(log a) == a / (sum_seg a + amax*1e-16)  -> per-node scalar.
// CSR (by dst) built on device each call. Aggregation kernel is LDS-free for
// high occupancy; MLP kernel holds the transposed weight tile in LDS.
// ---------------------------------------------------------------------------

#define WAVE 64

__global__ void k_count(const int* __restrict__ dst, int E, int* __restrict__ deg) {
    int e = blockIdx.x * blockDim.x + threadIdx.x;
    if (e < E) atomicAdd(&deg[dst[e]], 1);
}

__global__ __launch_bounds__(1024) void k_scan(const int* __restrict__ deg, int n,
                                               int* __restrict__ row_ptr,
                                               int* __restrict__ cursor) {
    __shared__ int sd[1024];
    int t = threadIdx.x;
    int C = (n + 1023) >> 10;
    int base = t * C;
    int lim = min(base + C, n);
    int lsum = 0;
    for (int i = base; i < lim; ++i) lsum += deg[i];
    sd[t] = lsum;
    __syncthreads();
    for (int off = 1; off < 1024; off <<= 1) {
        int v = (t >= off) ? sd[t - off] : 0;
        __syncthreads();
        sd[t] += v;
        __syncthreads();
    }
    int excl = sd[t] - lsum;
    if (t == 0) row_ptr[n] = sd[1023];
    int run = excl;
    for (int i = base; i < lim; ++i) {
        row_ptr[i] = run;
        cursor[i] = run;
        run += deg[i];
    }
}

__global__ void k_scatter(const int* __restrict__ src, const int* __restrict__ dst,
                          const float* __restrict__ adv, int E,
                          int* __restrict__ cursor,
                          int2* __restrict__ pair0, int2* __restrict__ pair1) {
    int e = blockIdx.x * blockDim.x + threadIdx.x;
    if (e < E) {
        int d = dst[e];
        int p = atomicAdd(&cursor[d], 1);
        int s = src[e];
        pair0[p] = make_int2(s, __float_as_int(adv[e]));
        pair1[p] = make_int2(s, __float_as_int(adv[E + e]));
    }
}

// ---- aggregation: one wave per node, LDS-free, 4x unrolled gathers ----
__global__ __launch_bounds__(512) void k_aggr(const float* __restrict__ rep_in,
                                              const int* __restrict__ row_ptr,
                                              const int2* __restrict__ pairs,
                                              float* __restrict__ xout, int n) {
    int wave = threadIdx.x >> 6, lane = threadIdx.x & 63;
    int node = blockIdx.x * 8 + wave;
    if (node >= n) return;
    int s0 = row_ptr[node], s1 = row_ptr[node + 1];
    // softmax denominator: att_e = a_e / (ssum + amax*1e-16)
    float amax = 0.f, ssum = 0.f;
    for (int s = s0 + lane; s < s1; s += WAVE) {
        float a = __int_as_float(pairs[s].y);
        amax = fmaxf(amax, a);
        ssum += a;
    }
#pragma unroll
    for (int m = 1; m < WAVE; m <<= 1) {
        amax = fmaxf(amax, __shfl_xor(amax, m));
        ssum += __shfl_xor(ssum, m);
    }
    float inv = (s1 > s0) ? 1.f / (ssum + amax * 1e-16f) : 0.f;

    float accx = 0.f, accy = 0.f;
    int s = s0;
    for (; s + 4 <= s1; s += 4) {
        int2 p0 = pairs[s];
        int2 p1 = pairs[s + 1];
        int2 p2 = pairs[s + 2];
        int2 p3 = pairs[s + 3];
        float2 r0 = *(const float2*)&rep_in[(size_t)p0.x * 128 + lane * 2];
        float2 r1 = *(const float2*)&rep_in[(size_t)p1.x * 128 + lane * 2];
        float2 r2 = *(const float2*)&rep_in[(size_t)p2.x * 128 + lane * 2];
        float2 r3 = *(const float2*)&rep_in[(size_t)p3.x * 128 + lane * 2];
        accx = fmaf(__int_as_float(p0.y), r0.x, accx);
        accy = fmaf(__int_as_float(p0.y), r0.y, accy);
        accx = fmaf(__int_as_float(p1.y), r1.x, accx);
        accy = fmaf(__int_as_float(p1.y), r1.y, accy);
        accx = fmaf(__int_as_float(p2.y), r2.x, accx);
        accy = fmaf(__int_as_float(p2.y), r2.y, accy);
        accx = fmaf(__int_as_float(p3.y), r3.x, accx);
        accy = fmaf(__int_as_float(p3.y), r3.y, accy);
    }
    for (; s < s1; ++s) {
        int2 p = pairs[s];
        float2 r = *(const float2*)&rep_in[(size_t)p.x * 128 + lane * 2];
        accx = fmaf(__int_as_float(p.y), r.x, accx);
        accy = fmaf(__int_as_float(p.y), r.y, accy);
    }
    float2 mine = *(const float2*)&rep_in[(size_t)node * 128 + lane * 2];
    float2 o;
    o.x = fmaf(accx, inv, mine.x);
    o.y = fmaf(accy, inv, mine.y);
    *(float2*)&xout[(size_t)node * 128 + lane * 2] = o;
}

// ---- MLP: rep_out = LN(gelu(x @ W^T + b)); 8 nodes per 512-thread block ----
__global__ __launch_bounds__(512) void k_mlp(const float* __restrict__ x,
                                             const float* __restrict__ W,
                                             const float* __restrict__ b,
                                             const float* __restrict__ lw,
                                             const float* __restrict__ lb,
                                             float* __restrict__ rep_out, int n) {
    __shared__ float Wt[128 * 129];  // Wt[k*129+o]
    __shared__ float xb[8][128];
    for (int idx = threadIdx.x; idx < 128 * 128; idx += 512) {
        int o = idx >> 7, k = idx & 127;
        Wt[k * 129 + o] = W[idx];
    }
    int wave = threadIdx.x >> 6, lane = threadIdx.x & 63;
    int node = blockIdx.x * 8 + wave;
    if (node < n) {
        float2 v = *(const float2*)&x[(size_t)node * 128 + lane * 2];
        xb[wave][lane * 2] = v.x;
        xb[wave][lane * 2 + 1] = v.y;
    }
    __syncthreads();
    if (node >= n) return;
    float a0 = 0.f, a1 = 0.f;
#pragma unroll 8
    for (int k = 0; k < 128; ++k) {
        float xk = xb[wave][k];
        a0 = fmaf(xk, Wt[k * 129 + lane], a0);
        a1 = fmaf(xk, Wt[k * 129 + 64 + lane], a1);
    }
    a0 += b[lane];
    a1 += b[lane + 64];
    float g0 = 0.5f * a0 * (1.f + erff(a0 * 0.70710678118654752f));
    float g1 = 0.5f * a1 * (1.f + erff(a1 * 0.70710678118654752f));
    float sv = g0 + g1;
#pragma unroll
    for (int m = 1; m < WAVE; m <<= 1) sv += __shfl_xor(sv, m);
    float mu = sv * (1.f / 128.f);
    float d0 = g0 - mu, d1 = g1 - mu;
    float vv = d0 * d0 + d1 * d1;
#pragma unroll
    for (int m = 1; m < WAVE; m <<= 1) vv += __shfl_xor(vv, m);
    float rstd = rsqrtf(vv * (1.f / 128.f) + 1e-5f);
    rep_out[(size_t)node * 128 + lane] = d0 * rstd * lw[lane] + lb[lane];
    rep_out[(size_t)node * 128 + 64 + lane] = d1 * rstd * lw[lane + 64] + lb[lane + 64];
}

// ---- input projection: rep = attr @ W^T + b ----
__global__ __launch_bounds__(512) void k_input(const float* __restrict__ attr,
                                               const float* __restrict__ W,
                                               const float* __restrict__ b,
                                               float* __restrict__ out, int n) {
    __shared__ float Wt[128 * 129];
    __shared__ float xb[8][128];
    for (int idx = threadIdx.x; idx < 128 * 128; idx += 512) {
        int o = idx >> 7, k = idx & 127;
        Wt[k * 129 + o] = W[idx];
    }
    int wave = threadIdx.x >> 6, lane = threadIdx.x & 63;
    int node = blockIdx.x * 8 + wave;
    if (node < n) {
        float2 v = *(const float2*)&attr[(size_t)node * 128 + lane * 2];
        xb[wave][lane * 2] = v.x;
        xb[wave][lane * 2 + 1] = v.y;
    }
    __syncthreads();
    if (node >= n) return;
    float a0 = 0.f, a1 = 0.f;
#pragma unroll 8
    for (int k = 0; k < 128; ++k) {
        float xk = xb[wave][k];
        a0 = fmaf(xk, Wt[k * 129 + lane], a0);
        a1 = fmaf(xk, Wt[k * 129 + 64 + lane], a1);
    }
    out[(size_t)node * 128 + lane] = a0 + b[lane];
    out[(size_t)node * 128 + 64 + lane] = a1 + b[64 + lane];
}

// ---- output projection: out = rep @ W_out^T + b_out (64 outputs) ----
__global__ __launch_bounds__(512) void k_out(const float* __restrict__ rep,
                                             const float* __restrict__ W,
                                             const float* __restrict__ b,
                                             float* __restrict__ out, int n) {
    __shared__ float Wt[128 * 65];  // Wt[k*65+o]
    __shared__ float xb[8][128];
    for (int idx = threadIdx.x; idx < 64 * 128; idx += 512) {
        int o = idx >> 7, k = idx & 127;
        Wt[k * 65 + o] = W[idx];
    }
    int wave = threadIdx.x >> 6, lane = threadIdx.x & 63;
    int node = blockIdx.x * 8 + wave;
    if (node < n) {
        float2 v = *(const float2*)&rep[(size_t)node * 128 + lane * 2];
        xb[wave][lane * 2] = v.x;
        xb[wave][lane * 2 + 1] = v.y;
    }
    __syncthreads();
    if (node >= n) return;
    float acc = 0.f;
#pragma unroll 8
    for (int k = 0; k < 128; ++k) acc = fmaf(xb[wave][k], Wt[k * 65 + lane], acc);
    out[(size_t)node * 64 + lane] = acc + b[lane];
}

extern "C" void kernel_launch(void* const* d_in, const int* in_sizes, int n_in,
                              void* d_out, int out_size, void* d_ws, size_t ws_size,
                              hipStream_t stream) {
    const float* node_attr = (const float*)d_in[0];
    const int* ei = (const int*)d_in[1];
    // d_in[2] = batch_idx (unused)
    const float* adv = (const float*)d_in[3];
    const float* W_inp = (const float*)d_in[4];
    const float* b_inp = (const float*)d_in[5];
    const float* W_a = (const float*)d_in[6];
    const float* b_a = (const float*)d_in[7];
    const float* ln_w = (const float*)d_in[8];
    const float* ln_b = (const float*)d_in[9];
    const float* W_out = (const float*)d_in[10];
    const float* b_out = (const float*)d_in[11];

    const int n = in_sizes[0] / 128;
    const int E = in_sizes[1] / 2;
    const int H = 128;

    // workspace: A, B (ping-pong n*H), pair0, pair1, deg, cursor, row_ptr
    float* A = (float*)d_ws;
    float* B = A + (size_t)n * H;
    int2* pair0 = (int2*)(B + (size_t)n * H);
    int2* pair1 = pair0 + E;
    int* deg = (int*)(pair1 + E);
    int* cursor = deg + n;
    int* row_ptr = cursor + n;

    const int* src = ei;
    const int* dst = ei + E;

    hipMemsetAsync(deg, 0, (size_t)n * sizeof(int), stream);

    int eb = (E + 255) / 256;
    k_count<<<eb, 256, 0, stream>>>(dst, E, deg);
    k_scan<<<1, 1024, 0, stream>>>(deg, n, row_ptr, cursor);
    k_scatter<<<eb, 256, 0, stream>>>(src, dst, adv, E, cursor, pair0, pair1);

    int nb8 = (n + 7) / 8;
    k_input<<<nb8, 512, 0, stream>>>(node_attr, W_inp, b_inp, A, n);

    // layer 0: B = aggr(A); A = mlp(B)
    k_aggr<<<nb8, 512, 0, stream>>>(A, row_ptr, pair0, B, n);
    k_mlp<<<nb8, 512, 0, stream>>>(B, W_a, b_a, ln_w, ln_b, A, n);
    // layer 1: B = aggr(A); A = mlp(B)
    k_aggr<<<nb8, 512, 0, stream>>>(A, row_ptr, pair1, B, n);
    k_mlp<<<nb8, 512, 0, stream>>>(B, W_a + 128 * 128, b_a + 128,
                                   ln_w + 128, ln_b + 128, A, n);

    k_out<<<nb8, 512, 0, stream>>>(A, W_out, b_out, (float*)d_out, n);
}

// Round 3
// 711.432 us; speedup vs baseline: 2.2223x; 1.1565x over previous
//
#include <hip/hip_runtime.h>
#include <hip/hip_bf16.h>
#include <math.h>

// ---------------------------------------------------------------------------
// GNN: rep = attr @ W_inp^T + b
//      2x { x = (segsoftmax-weighted aggr of rep[src] by dst) + rep;
//           rep = LN(gelu(x @ W_a^T + b)) }
//      out = rep @ W_out^T + b_out
// segment_softmax(log a) == a / (sum_seg a + amax*1e-16)  -> per-node scalar.
// CSR by dst built per call: deg count -> scan -> 3x 4B scatter (csr_src,
// csr_a0, csr_a1; 2.4MB/XCD => L2-resident, minimal write amplification).
// Intermediate node features stored as packed bf16x2 (halves gather traffic);
// all accumulation in f32.
// ---------------------------------------------------------------------------

#define WAVE 64

static __device__ __forceinline__ float bf2f(uint u16) {
    union { uint i; float f; } c;
    c.i = u16 << 16;
    return c.f;
}
static __device__ __forceinline__ uint f2bf(float f) {
    uint x = __float_as_uint(f);
    return (x + 0x7FFFu + ((x >> 16) & 1u)) >> 16;  // RNE
}

__global__ void k_count(const int* __restrict__ dst, int E, int* __restrict__ deg) {
    int e = blockIdx.x * blockDim.x + threadIdx.x;
    if (e < E) atomicAdd(&deg[dst[e]], 1);
}

__global__ __launch_bounds__(1024) void k_scan(const int* __restrict__ deg, int n,
                                               int* __restrict__ row_ptr,
                                               int* __restrict__ cursor) {
    __shared__ int sd[1024];
    int t = threadIdx.x;
    int C = (n + 1023) >> 10;
    int base = t * C;
    int lim = min(base + C, n);
    int lsum = 0;
    for (int i = base; i < lim; ++i) lsum += deg[i];
    sd[t] = lsum;
    __syncthreads();
    for (int off = 1; off < 1024; off <<= 1) {
        int v = (t >= off) ? sd[t - off] : 0;
        __syncthreads();
        sd[t] += v;
        __syncthreads();
    }
    int excl = sd[t] - lsum;
    if (t == 0) row_ptr[n] = sd[1023];
    int run = excl;
    for (int i = base; i < lim; ++i) {
        row_ptr[i] = run;
        cursor[i] = run;
        run += deg[i];
    }
}

__global__ void k_scatter(const int* __restrict__ src, const int* __restrict__ dst,
                          const float* __restrict__ adv, int E,
                          int* __restrict__ cursor,
                          int* __restrict__ csr_src,
                          float* __restrict__ csr_a0,
                          float* __restrict__ csr_a1) {
    int e = blockIdx.x * blockDim.x + threadIdx.x;
    if (e < E) {
        int d = dst[e];
        int p = atomicAdd(&cursor[d], 1);
        csr_src[p] = src[e];
        csr_a0[p] = adv[e];
        csr_a1[p] = adv[E + e];
    }
}

// ---- aggregation: one wave per node; rep is packed bf16x2 (1 dword/lane) ----
__global__ __launch_bounds__(512) void k_aggr(const uint* __restrict__ rep32,
                                              const int* __restrict__ row_ptr,
                                              const int* __restrict__ csr_src,
                                              const float* __restrict__ csr_a,
                                              uint* __restrict__ xout, int n) {
    int wave = threadIdx.x >> 6, lane = threadIdx.x & 63;
    int node = blockIdx.x * 8 + wave;
    if (node >= n) return;
    int s0 = row_ptr[node], s1 = row_ptr[node + 1];
    // softmax denominator: att_e = a_e / (ssum + amax*1e-16)
    float amax = 0.f, ssum = 0.f;
    for (int s = s0 + lane; s < s1; s += WAVE) {
        float a = csr_a[s];
        amax = fmaxf(amax, a);
        ssum += a;
    }
#pragma unroll
    for (int m = 1; m < WAVE; m <<= 1) {
        amax = fmaxf(amax, __shfl_xor(amax, m));
        ssum += __shfl_xor(ssum, m);
    }
    float inv = (s1 > s0) ? 1.f / (ssum + amax * 1e-16f) : 0.f;

    float accx = 0.f, accy = 0.f;
    int s = s0;
    for (; s + 4 <= s1; s += 4) {
        int i0 = csr_src[s], i1 = csr_src[s + 1], i2 = csr_src[s + 2], i3 = csr_src[s + 3];
        float a0 = csr_a[s], a1 = csr_a[s + 1], a2 = csr_a[s + 2], a3 = csr_a[s + 3];
        uint r0 = rep32[(size_t)i0 * 64 + lane];
        uint r1 = rep32[(size_t)i1 * 64 + lane];
        uint r2 = rep32[(size_t)i2 * 64 + lane];
        uint r3 = rep32[(size_t)i3 * 64 + lane];
        accx = fmaf(a0, bf2f(r0 & 0xffffu), accx);
        accy = fmaf(a0, bf2f(r0 >> 16), accy);
        accx = fmaf(a1, bf2f(r1 & 0xffffu), accx);
        accy = fmaf(a1, bf2f(r1 >> 16), accy);
        accx = fmaf(a2, bf2f(r2 & 0xffffu), accx);
        accy = fmaf(a2, bf2f(r2 >> 16), accy);
        accx = fmaf(a3, bf2f(r3 & 0xffffu), accx);
        accy = fmaf(a3, bf2f(r3 >> 16), accy);
    }
    for (; s < s1; ++s) {
        int i0 = csr_src[s];
        float a0 = csr_a[s];
        uint r0 = rep32[(size_t)i0 * 64 + lane];
        accx = fmaf(a0, bf2f(r0 & 0xffffu), accx);
        accy = fmaf(a0, bf2f(r0 >> 16), accy);
    }
    uint m = rep32[(size_t)node * 64 + lane];
    float ox = fmaf(accx, inv, bf2f(m & 0xffffu));
    float oy = fmaf(accy, inv, bf2f(m >> 16));
    xout[(size_t)node * 64 + lane] = f2bf(ox) | (f2bf(oy) << 16);
}

// ---- input projection: rep(bf16) = attr(f32) @ W^T + b ----
__global__ __launch_bounds__(512) void k_input(const float* __restrict__ attr,
                                               const float* __restrict__ W,
                                               const float* __restrict__ b,
                                               uint* __restrict__ out32, int n) {
    __shared__ float Wt[128 * 130];  // Wt[k*130+o], pad keeps float2 8B-aligned
    __shared__ float xb[8][128];
    for (int idx = threadIdx.x; idx < 128 * 128; idx += 512) {
        int o = idx >> 7, k = idx & 127;
        Wt[k * 130 + o] = W[idx];
    }
    int wave = threadIdx.x >> 6, lane = threadIdx.x & 63;
    int node = blockIdx.x * 8 + wave;
    if (node < n) {
        float2 v = *(const float2*)&attr[(size_t)node * 128 + lane * 2];
        *(float2*)&xb[wave][lane * 2] = v;
    }
    __syncthreads();
    if (node >= n) return;
    float a0 = 0.f, a1 = 0.f;
#pragma unroll 8
    for (int k = 0; k < 128; ++k) {
        float xk = xb[wave][k];
        float2 w = *(const float2*)&Wt[k * 130 + lane * 2];
        a0 = fmaf(xk, w.x, a0);
        a1 = fmaf(xk, w.y, a1);
    }
    float2 bb = *(const float2*)&b[lane * 2];
    a0 += bb.x;
    a1 += bb.y;
    out32[(size_t)node * 64 + lane] = f2bf(a0) | (f2bf(a1) << 16);
}

// ---- MLP: rep(bf16) = LN(gelu(x(bf16) @ W^T + b)) ----
__global__ __launch_bounds__(512) void k_mlp(const uint* __restrict__ x32,
                                             const float* __restrict__ W,
                                             const float* __restrict__ b,
                                             const float* __restrict__ lw,
                                             const float* __restrict__ lb,
                                             uint* __restrict__ out32, int n) {
    __shared__ float Wt[128 * 130];
    __shared__ float xb[8][128];
    for (int idx = threadIdx.x; idx < 128 * 128; idx += 512) {
        int o = idx >> 7, k = idx & 127;
        Wt[k * 130 + o] = W[idx];
    }
    int wave = threadIdx.x >> 6, lane = threadIdx.x & 63;
    int node = blockIdx.x * 8 + wave;
    if (node < n) {
        uint v = x32[(size_t)node * 64 + lane];
        xb[wave][lane * 2] = bf2f(v & 0xffffu);
        xb[wave][lane * 2 + 1] = bf2f(v >> 16);
    }
    __syncthreads();
    if (node >= n) return;
    float a0 = 0.f, a1 = 0.f;
#pragma unroll 8
    for (int k = 0; k < 128; ++k) {
        float xk = xb[wave][k];
        float2 w = *(const float2*)&Wt[k * 130 + lane * 2];
        a0 = fmaf(xk, w.x, a0);
        a1 = fmaf(xk, w.y, a1);
    }
    float2 bb = *(const float2*)&b[lane * 2];
    a0 += bb.x;
    a1 += bb.y;
    float g0 = 0.5f * a0 * (1.f + erff(a0 * 0.70710678118654752f));
    float g1 = 0.5f * a1 * (1.f + erff(a1 * 0.70710678118654752f));
    float sv = g0 + g1;
#pragma unroll
    for (int m = 1; m < WAVE; m <<= 1) sv += __shfl_xor(sv, m);
    float mu = sv * (1.f / 128.f);
    float d0 = g0 - mu, d1 = g1 - mu;
    float vv = d0 * d0 + d1 * d1;
#pragma unroll
    for (int m = 1; m < WAVE; m <<= 1) vv += __shfl_xor(vv, m);
    float rstd = rsqrtf(vv * (1.f / 128.f) + 1e-5f);
    float2 w2 = *(const float2*)&lw[lane * 2];
    float2 b2 = *(const float2*)&lb[lane * 2];
    float o0 = d0 * rstd * w2.x + b2.x;
    float o1 = d1 * rstd * w2.y + b2.y;
    out32[(size_t)node * 64 + lane] = f2bf(o0) | (f2bf(o1) << 16);
}

// ---- output projection: out(f32) = rep(bf16) @ W_out^T + b_out (64 outs) ----
__global__ __launch_bounds__(512) void k_out(const uint* __restrict__ rep32,
                                             const float* __restrict__ W,
                                             const float* __restrict__ b,
                                             float* __restrict__ out, int n) {
    __shared__ float Wt[128 * 65];  // Wt[k*65+o]
    __shared__ float xb[8][128];
    for (int idx = threadIdx.x; idx < 64 * 128; idx += 512) {
        int o = idx >> 7, k = idx & 127;
        Wt[k * 65 + o] = W[idx];
    }
    int wave = threadIdx.x >> 6, lane = threadIdx.x & 63;
    int node = blockIdx.x * 8 + wave;
    if (node < n) {
        uint v = rep32[(size_t)node * 64 + lane];
        xb[wave][lane * 2] = bf2f(v & 0xffffu);
        xb[wave][lane * 2 + 1] = bf2f(v >> 16);
    }
    __syncthreads();
    if (node >= n) return;
    float acc = 0.f;
#pragma unroll 8
    for (int k = 0; k < 128; ++k) acc = fmaf(xb[wave][k], Wt[k * 65 + lane], acc);
    out[(size_t)node * 64 + lane] = acc + b[lane];
}

extern "C" void kernel_launch(void* const* d_in, const int* in_sizes, int n_in,
                              void* d_out, int out_size, void* d_ws, size_t ws_size,
                              hipStream_t stream) {
    const float* node_attr = (const float*)d_in[0];
    const int* ei = (const int*)d_in[1];
    // d_in[2] = batch_idx (unused)
    const float* adv = (const float*)d_in[3];
    const float* W_inp = (const float*)d_in[4];
    const float* b_inp = (const float*)d_in[5];
    const float* W_a = (const float*)d_in[6];
    const float* b_a = (const float*)d_in[7];
    const float* ln_w = (const float*)d_in[8];
    const float* ln_b = (const float*)d_in[9];
    const float* W_out = (const float*)d_in[10];
    const float* b_out = (const float*)d_in[11];

    const int n = in_sizes[0] / 128;
    const int E = in_sizes[1] / 2;

    // workspace: A, B (bf16x2 packed, n*64 dwords each), csr arrays, deg/cursor/row_ptr
    uint* A = (uint*)d_ws;
    uint* B = A + (size_t)n * 64;
    int* csr_src = (int*)(B + (size_t)n * 64);
    float* csr_a0 = (float*)(csr_src + E);
    float* csr_a1 = csr_a0 + E;
    int* deg = (int*)(csr_a1 + E);
    int* cursor = deg + n;
    int* row_ptr = cursor + n;  // n+1

    const int* src = ei;
    const int* dst = ei + E;

    hipMemsetAsync(deg, 0, (size_t)n * sizeof(int), stream);

    int eb = (E + 255) / 256;
    k_count<<<eb, 256, 0, stream>>>(dst, E, deg);
    k_scan<<<1, 1024, 0, stream>>>(deg, n, row_ptr, cursor);
    k_scatter<<<eb, 256, 0, stream>>>(src, dst, adv, E, cursor, csr_src, csr_a0, csr_a1);

    int nb8 = (n + 7) / 8;
    k_input<<<nb8, 512, 0, stream>>>(node_attr, W_inp, b_inp, A, n);

    // layer 0: B = aggr(A); A = mlp(B)
    k_aggr<<<nb8, 512, 0, stream>>>(A, row_ptr, csr_src, csr_a0, B, n);
    k_mlp<<<nb8, 512, 0, stream>>>(B, W_a, b_a, ln_w, ln_b, A, n);
    // layer 1: B = aggr(A); A = mlp(B)
    k_aggr<<<nb8, 512, 0, stream>>>(A, row_ptr, csr_src, csr_a1, B, n);
    k_mlp<<<nb8, 512, 0, stream>>>(B, W_a + 128 * 128, b_a + 128,
                                   ln_w + 128, ln_b + 128, A, n);

    k_out<<<nb8, 512, 0, stream>>>(A, W_out, b_out, (float*)d_out, n);
}

// Round 4
// 649.229 us; speedup vs baseline: 2.4352x; 1.0958x over previous
//
#include <hip/hip_runtime.h>
#include <hip/hip_bf16.h>
#include <math.h>

// ---------------------------------------------------------------------------
// GNN: rep = attr @ W_inp^T + b
//      2x { x = (segsoftmax-weighted aggr of rep[src] by dst) + rep;
//           rep = LN(gelu(x @ W_a^T + b)) }
//      out = rep @ W_out^T + b_out
// segment_softmax(log a) == a / (sum_seg a + amax*1e-16)  -> per-node scalar.
// CSR by dst built per call: deg count -> multi-block scan -> scatter of ONE
// 16B record per edge (src, a0, a1, pad) to minimize write amplification.
// Intermediate node features stored as packed bf16x2; f32 accumulation.
// ---------------------------------------------------------------------------

#define WAVE 64

static __device__ __forceinline__ float bf2f(uint u16) {
    union { uint i; float f; } c;
    c.i = u16 << 16;
    return c.f;
}
static __device__ __forceinline__ uint f2bf(float f) {
    uint x = __float_as_uint(f);
    return (x + 0x7FFFu + ((x >> 16) & 1u)) >> 16;  // RNE
}

__global__ void k_count(const int* __restrict__ dst, int E, int* __restrict__ deg) {
    int e = blockIdx.x * blockDim.x + threadIdx.x;
    if (e < E) atomicAdd(&deg[dst[e]], 1);
}

// ---- 3-phase scan over deg[n] (n <= 256*256) ----
__global__ __launch_bounds__(256) void k_scan1(const int* __restrict__ deg, int n,
                                               int* __restrict__ excl,
                                               int* __restrict__ bsum) {
    __shared__ int sd[256];
    int t = threadIdx.x, i = blockIdx.x * 256 + t;
    int v = (i < n) ? deg[i] : 0;
    sd[t] = v;
    __syncthreads();
    for (int off = 1; off < 256; off <<= 1) {
        int u = (t >= off) ? sd[t - off] : 0;
        __syncthreads();
        sd[t] += u;
        __syncthreads();
    }
    if (i < n) excl[i] = sd[t] - v;
    if (t == 255) bsum[blockIdx.x] = sd[255];
}

__global__ __launch_bounds__(256) void k_scan2(int* __restrict__ bsum, int nb) {
    __shared__ int sd[256];
    int t = threadIdx.x;
    int v = (t < nb) ? bsum[t] : 0;
    sd[t] = v;
    __syncthreads();
    for (int off = 1; off < 256; off <<= 1) {
        int u = (t >= off) ? sd[t - off] : 0;
        __syncthreads();
        sd[t] += u;
        __syncthreads();
    }
    if (t < nb) bsum[t] = sd[t] - v;  // exclusive block offsets
}

__global__ __launch_bounds__(256) void k_scan3(const int* __restrict__ deg,
                                               const int* __restrict__ excl,
                                               const int* __restrict__ bsum, int n,
                                               int* __restrict__ row_ptr,
                                               int* __restrict__ cursor) {
    int i = blockIdx.x * 256 + threadIdx.x;
    if (i < n) {
        int rp = bsum[blockIdx.x] + excl[i];
        row_ptr[i] = rp;
        cursor[i] = rp;
        if (i == n - 1) row_ptr[n] = rp + deg[i];
    }
}

// ---- scatter: one 16B record per edge ----
__global__ void k_scatter(const int* __restrict__ src, const int* __restrict__ dst,
                          const float* __restrict__ adv, int E,
                          int* __restrict__ cursor, int4* __restrict__ csr) {
    int e = blockIdx.x * blockDim.x + threadIdx.x;
    if (e < E) {
        int d = dst[e];
        int p = atomicAdd(&cursor[d], 1);
        csr[p] = make_int4(src[e], __float_as_int(adv[e]), __float_as_int(adv[E + e]), 0);
    }
}

// ---- aggregation: one wave per node; rep packed bf16x2 (1 dword/lane) ----
// csr viewed as int[4*E]; att of this layer at element offset aoff (1 or 2).
__global__ __launch_bounds__(512) void k_aggr(const uint* __restrict__ rep32,
                                              const int* __restrict__ row_ptr,
                                              const int* __restrict__ csr, int aoff,
                                              uint* __restrict__ xout, int n) {
    int wave = threadIdx.x >> 6, lane = threadIdx.x & 63;
    int node = blockIdx.x * 8 + wave;
    if (node >= n) return;
    int s0 = row_ptr[node], s1 = row_ptr[node + 1];
    // softmax denominator: att_e = a_e / (ssum + amax*1e-16)
    float amax = 0.f, ssum = 0.f;
    for (int s = s0 + lane; s < s1; s += WAVE) {
        float a = __int_as_float(csr[4 * s + aoff]);
        amax = fmaxf(amax, a);
        ssum += a;
    }
#pragma unroll
    for (int m = 1; m < WAVE; m <<= 1) {
        amax = fmaxf(amax, __shfl_xor(amax, m));
        ssum += __shfl_xor(ssum, m);
    }
    float inv = (s1 > s0) ? 1.f / (ssum + amax * 1e-16f) : 0.f;

    float accx = 0.f, accy = 0.f;
    int s = s0;
    for (; s + 4 <= s1; s += 4) {
        int b = 4 * s;  // wave-uniform -> scalar loads
        int i0 = csr[b], i1 = csr[b + 4], i2 = csr[b + 8], i3 = csr[b + 12];
        float a0 = __int_as_float(csr[b + aoff]);
        float a1 = __int_as_float(csr[b + 4 + aoff]);
        float a2 = __int_as_float(csr[b + 8 + aoff]);
        float a3 = __int_as_float(csr[b + 12 + aoff]);
        uint r0 = rep32[(size_t)i0 * 64 + lane];
        uint r1 = rep32[(size_t)i1 * 64 + lane];
        uint r2 = rep32[(size_t)i2 * 64 + lane];
        uint r3 = rep32[(size_t)i3 * 64 + lane];
        accx = fmaf(a0, bf2f(r0 & 0xffffu), accx);
        accy = fmaf(a0, bf2f(r0 >> 16), accy);
        accx = fmaf(a1, bf2f(r1 & 0xffffu), accx);
        accy = fmaf(a1, bf2f(r1 >> 16), accy);
        accx = fmaf(a2, bf2f(r2 & 0xffffu), accx);
        accy = fmaf(a2, bf2f(r2 >> 16), accy);
        accx = fmaf(a3, bf2f(r3 & 0xffffu), accx);
        accy = fmaf(a3, bf2f(r3 >> 16), accy);
    }
    for (; s < s1; ++s) {
        int b = 4 * s;
        int i0 = csr[b];
        float a0 = __int_as_float(csr[b + aoff]);
        uint r0 = rep32[(size_t)i0 * 64 + lane];
        accx = fmaf(a0, bf2f(r0 & 0xffffu), accx);
        accy = fmaf(a0, bf2f(r0 >> 16), accy);
    }
    uint m = rep32[(size_t)node * 64 + lane];
    float ox = fmaf(accx, inv, bf2f(m & 0xffffu));
    float oy = fmaf(accy, inv, bf2f(m >> 16));
    xout[(size_t)node * 64 + lane] = f2bf(ox) | (f2bf(oy) << 16);
}

// ---- input projection: rep(bf16) = attr(f32) @ W^T + b ----
__global__ __launch_bounds__(512) void k_input(const float* __restrict__ attr,
                                               const float* __restrict__ W,
                                               const float* __restrict__ b,
                                               uint* __restrict__ out32, int n) {
    __shared__ float Wt[128 * 130];  // Wt[k*130+o], pad keeps float2 8B-aligned
    __shared__ float xb[8][128];
    for (int idx = threadIdx.x; idx < 128 * 128; idx += 512) {
        int o = idx >> 7, k = idx & 127;
        Wt[k * 130 + o] = W[idx];
    }
    int wave = threadIdx.x >> 6, lane = threadIdx.x & 63;
    int node = blockIdx.x * 8 + wave;
    if (node < n) {
        float2 v = *(const float2*)&attr[(size_t)node * 128 + lane * 2];
        *(float2*)&xb[wave][lane * 2] = v;
    }
    __syncthreads();
    if (node >= n) return;
    float a0 = 0.f, a1 = 0.f;
#pragma unroll 8
    for (int k = 0; k < 128; ++k) {
        float xk = xb[wave][k];
        float2 w = *(const float2*)&Wt[k * 130 + lane * 2];
        a0 = fmaf(xk, w.x, a0);
        a1 = fmaf(xk, w.y, a1);
    }
    float2 bb = *(const float2*)&b[lane * 2];
    a0 += bb.x;
    a1 += bb.y;
    out32[(size_t)node * 64 + lane] = f2bf(a0) | (f2bf(a1) << 16);
}

// ---- MLP: rep(bf16) = LN(gelu(x(bf16) @ W^T + b)) ----
__global__ __launch_bounds__(512) void k_mlp(const uint* __restrict__ x32,
                                             const float* __restrict__ W,
                                             const float* __restrict__ b,
                                             const float* __restrict__ lw,
                                             const float* __restrict__ lb,
                                             uint* __restrict__ out32, int n) {
    __shared__ float Wt[128 * 130];
    __shared__ float xb[8][128];
    for (int idx = threadIdx.x; idx < 128 * 128; idx += 512) {
        int o = idx >> 7, k = idx & 127;
        Wt[k * 130 + o] = W[idx];
    }
    int wave = threadIdx.x >> 6, lane = threadIdx.x & 63;
    int node = blockIdx.x * 8 + wave;
    if (node < n) {
        uint v = x32[(size_t)node * 64 + lane];
        xb[wave][lane * 2] = bf2f(v & 0xffffu);
        xb[wave][lane * 2 + 1] = bf2f(v >> 16);
    }
    __syncthreads();
    if (node >= n) return;
    float a0 = 0.f, a1 = 0.f;
#pragma unroll 8
    for (int k = 0; k < 128; ++k) {
        float xk = xb[wave][k];
        float2 w = *(const float2*)&Wt[k * 130 + lane * 2];
        a0 = fmaf(xk, w.x, a0);
        a1 = fmaf(xk, w.y, a1);
    }
    float2 bb = *(const float2*)&b[lane * 2];
    a0 += bb.x;
    a1 += bb.y;
    float g0 = 0.5f * a0 * (1.f + erff(a0 * 0.70710678118654752f));
    float g1 = 0.5f * a1 * (1.f + erff(a1 * 0.70710678118654752f));
    float sv = g0 + g1;
#pragma unroll
    for (int m = 1; m < WAVE; m <<= 1) sv += __shfl_xor(sv, m);
    float mu = sv * (1.f / 128.f);
    float d0 = g0 - mu, d1 = g1 - mu;
    float vv = d0 * d0 + d1 * d1;
#pragma unroll
    for (int m = 1; m < WAVE; m <<= 1) vv += __shfl_xor(vv, m);
    float rstd = rsqrtf(vv * (1.f / 128.f) + 1e-5f);
    float2 w2 = *(const float2*)&lw[lane * 2];
    float2 b2 = *(const float2*)&lb[lane * 2];
    float o0 = d0 * rstd * w2.x + b2.x;
    float o1 = d1 * rstd * w2.y + b2.y;
    out32[(size_t)node * 64 + lane] = f2bf(o0) | (f2bf(o1) << 16);
}

// ---- output projection: out(f32) = rep(bf16) @ W_out^T + b_out (64 outs) ----
__global__ __launch_bounds__(512) void k_out(const uint* __restrict__ rep32,
                                             const float* __restrict__ W,
                                             const float* __restrict__ b,
                                             float* __restrict__ out, int n) {
    __shared__ float Wt[128 * 65];  // Wt[k*65+o]
    __shared__ float xb[8][128];
    for (int idx = threadIdx.x; idx < 64 * 128; idx += 512) {
        int o = idx >> 7, k = idx & 127;
        Wt[k * 65 + o] = W[idx];
    }
    int wave = threadIdx.x >> 6, lane = threadIdx.x & 63;
    int node = blockIdx.x * 8 + wave;
    if (node < n) {
        uint v = rep32[(size_t)node * 64 + lane];
        xb[wave][lane * 2] = bf2f(v & 0xffffu);
        xb[wave][lane * 2 + 1] = bf2f(v >> 16);
    }
    __syncthreads();
    if (node >= n) return;
    float acc = 0.f;
#pragma unroll 8
    for (int k = 0; k < 128; ++k) acc = fmaf(xb[wave][k], Wt[k * 65 + lane], acc);
    out[(size_t)node * 64 + lane] = acc + b[lane];
}

extern "C" void kernel_launch(void* const* d_in, const int* in_sizes, int n_in,
                              void* d_out, int out_size, void* d_ws, size_t ws_size,
                              hipStream_t stream) {
    const float* node_attr = (const float*)d_in[0];
    const int* ei = (const int*)d_in[1];
    // d_in[2] = batch_idx (unused)
    const float* adv = (const float*)d_in[3];
    const float* W_inp = (const float*)d_in[4];
    const float* b_inp = (const float*)d_in[5];
    const float* W_a = (const float*)d_in[6];
    const float* b_a = (const float*)d_in[7];
    const float* ln_w = (const float*)d_in[8];
    const float* ln_b = (const float*)d_in[9];
    const float* W_out = (const float*)d_in[10];
    const float* b_out = (const float*)d_in[11];

    const int n = in_sizes[0] / 128;
    const int E = in_sizes[1] / 2;

    // workspace: A, B (bf16x2 packed, n*64 dwords), csr (E int4), scan temps
    uint* A = (uint*)d_ws;
    uint* B = A + (size_t)n * 64;
    int4* csr = (int4*)(B + (size_t)n * 64);   // 16B-aligned: 2*n*256B offset
    int* deg = (int*)(csr + E);
    int* cursor = deg + n;
    int* excl = cursor + n;
    int* row_ptr = excl + n;   // n+1
    int* bsum = row_ptr + n + 1;  // 256

    const int* src = ei;
    const int* dst = ei + E;

    hipMemsetAsync(deg, 0, (size_t)n * sizeof(int), stream);

    int eb = (E + 255) / 256;
    int nbs = (n + 255) / 256;  // 196 blocks (n <= 65536 supported by k_scan2)
    k_count<<<eb, 256, 0, stream>>>(dst, E, deg);
    k_scan1<<<nbs, 256, 0, stream>>>(deg, n, excl, bsum);
    k_scan2<<<1, 256, 0, stream>>>(bsum, nbs);
    k_scan3<<<nbs, 256, 0, stream>>>(deg, excl, bsum, n, row_ptr, cursor);
    k_scatter<<<eb, 256, 0, stream>>>(src, dst, adv, E, cursor, csr);

    int nb8 = (n + 7) / 8;
    k_input<<<nb8, 512, 0, stream>>>(node_attr, W_inp, b_inp, A, n);

    // layer 0: B = aggr(A); A = mlp(B)
    k_aggr<<<nb8, 512, 0, stream>>>(A, row_ptr, (const int*)csr, 1, B, n);
    k_mlp<<<nb8, 512, 0, stream>>>(B, W_a, b_a, ln_w, ln_b, A, n);
    // layer 1: B = aggr(A); A = mlp(B)
    k_aggr<<<nb8, 512, 0, stream>>>(A, row_ptr, (const int*)csr, 2, B, n);
    k_mlp<<<nb8, 512, 0, stream>>>(B, W_a + 128 * 128, b_a + 128,
                                   ln_w + 128, ln_b + 128, A, n);

    k_out<<<nb8, 512, 0, stream>>>(A, W_out, b_out, (float*)d_out, n);
}

// Round 5
// 609.105 us; speedup vs baseline: 2.5956x; 1.0659x over previous
//
#include <hip/hip_runtime.h>
#include <hip/hip_bf16.h>
#include <math.h>

// ---------------------------------------------------------------------------
// GNN: rep = attr @ W_inp^T + b
//      2x { x = (segsoftmax-weighted aggr of rep[src] by dst) + rep;
//           rep = LN(gelu(x @ W_a^T + b)) }
//      out = rep @ W_out^T + b_out
// segment_softmax(log a) == a / (ssum + amax*1e-16) -> per-node scalar, folded
// in post-aggregation. CSR by dst rebuilt per call. Scatter is XCD-partitioned:
// blockIdx&7 -> dst partition, so each partition's random writes come from one
// XCD and merge in its L2 (kills the 64B/record partial-line eviction amp).
// Node features stored packed bf16x2; f32 accumulation everywhere.
// ---------------------------------------------------------------------------

#define WAVE 64

static __device__ __forceinline__ float bf2f(uint u16) {
    union { uint i; float f; } c;
    c.i = u16 << 16;
    return c.f;
}
static __device__ __forceinline__ uint f2bf(float f) {
    uint x = __float_as_uint(f);
    return (x + 0x7FFFu + ((x >> 16) & 1u)) >> 16;  // RNE
}

__global__ void k_count(const int* __restrict__ dst, int E, int* __restrict__ deg) {
    int e = blockIdx.x * blockDim.x + threadIdx.x;
    if (e < E) atomicAdd(&deg[dst[e]], 1);
}

// ---- 3-phase scan over deg[n] (n <= 256*256) ----
__global__ __launch_bounds__(256) void k_scan1(const int* __restrict__ deg, int n,
                                               int* __restrict__ excl,
                                               int* __restrict__ bsum) {
    __shared__ int sd[256];
    int t = threadIdx.x, i = blockIdx.x * 256 + t;
    int v = (i < n) ? deg[i] : 0;
    sd[t] = v;
    __syncthreads();
    for (int off = 1; off < 256; off <<= 1) {
        int u = (t >= off) ? sd[t - off] : 0;
        __syncthreads();
        sd[t] += u;
        __syncthreads();
    }
    if (i < n) excl[i] = sd[t] - v;
    if (t == 255) bsum[blockIdx.x] = sd[255];
}

__global__ __launch_bounds__(256) void k_scan2(int* __restrict__ bsum, int nb) {
    __shared__ int sd[256];
    int t = threadIdx.x;
    int v = (t < nb) ? bsum[t] : 0;
    sd[t] = v;
    __syncthreads();
    for (int off = 1; off < 256; off <<= 1) {
        int u = (t >= off) ? sd[t - off] : 0;
        __syncthreads();
        sd[t] += u;
        __syncthreads();
    }
    if (t < nb) bsum[t] = sd[t] - v;  // exclusive block offsets
}

__global__ __launch_bounds__(256) void k_scan3(const int* __restrict__ deg,
                                               const int* __restrict__ excl,
                                               const int* __restrict__ bsum, int n,
                                               int* __restrict__ row_ptr,
                                               int* __restrict__ cursor) {
    int i = blockIdx.x * 256 + threadIdx.x;
    if (i < n) {
        int rp = bsum[blockIdx.x] + excl[i];
        row_ptr[i] = rp;
        cursor[i] = rp;
        if (i == n - 1) row_ptr[n] = rp + deg[i];
    }
}

// ---- scatter: XCD-partitioned. blockIdx&7 selects a dst range; with the
// round-robin block->XCD dispatch all writes to that range come from one XCD
// and coalesce in its L2. Each chunk of 4096 edges is scanned by 8 blocks. ----
#define SCHUNK 4096
__global__ __launch_bounds__(256) void k_scatter(const int* __restrict__ src,
                                                 const int* __restrict__ dst,
                                                 const float* __restrict__ adv, int E,
                                                 int n, int* __restrict__ cursor,
                                                 int4* __restrict__ csr) {
    int part = blockIdx.x & 7;
    int chunk = blockIdx.x >> 3;
    int PART = (n + 7) >> 3;
    int lo = part * PART, hi = lo + PART;
    int base = chunk * SCHUNK + threadIdx.x;
#pragma unroll
    for (int i = 0; i < SCHUNK / 256; ++i) {
        int e = base + i * 256;
        if (e < E) {
            int d = dst[e];
            if (d >= lo && d < hi) {
                int p = atomicAdd(&cursor[d], 1);
                csr[p] = make_int4(src[e], __float_as_int(adv[e]),
                                   __float_as_int(adv[E + e]), 0);
            }
        }
    }
}

// ---- aggregation: one wave per node, single pass; rep packed bf16x2.
// ssum/amax computed redundantly by all lanes (broadcast csr reads), inv
// applied at the end. aoff selects layer-0 (y) or layer-1 (z) attention. ----
__global__ __launch_bounds__(512) void k_aggr(const uint* __restrict__ rep32,
                                              const int* __restrict__ row_ptr,
                                              const int4* __restrict__ csr, int aoff,
                                              uint* __restrict__ xout, int n) {
    int wave = threadIdx.x >> 6, lane = threadIdx.x & 63;
    int node = blockIdx.x * 8 + wave;
    if (node >= n) return;
    int s0 = row_ptr[node], s1 = row_ptr[node + 1];
    float accx = 0.f, accy = 0.f, ssum = 0.f, amax = 0.f;
    int s = s0;
    for (; s + 8 <= s1; s += 8) {
        int4 c0 = csr[s], c1 = csr[s + 1], c2 = csr[s + 2], c3 = csr[s + 3];
        int4 c4 = csr[s + 4], c5 = csr[s + 5], c6 = csr[s + 6], c7 = csr[s + 7];
        float a0 = __int_as_float(aoff == 1 ? c0.y : c0.z);
        float a1 = __int_as_float(aoff == 1 ? c1.y : c1.z);
        float a2 = __int_as_float(aoff == 1 ? c2.y : c2.z);
        float a3 = __int_as_float(aoff == 1 ? c3.y : c3.z);
        float a4 = __int_as_float(aoff == 1 ? c4.y : c4.z);
        float a5 = __int_as_float(aoff == 1 ? c5.y : c5.z);
        float a6 = __int_as_float(aoff == 1 ? c6.y : c6.z);
        float a7 = __int_as_float(aoff == 1 ? c7.y : c7.z);
        uint r0 = rep32[(size_t)c0.x * 64 + lane];
        uint r1 = rep32[(size_t)c1.x * 64 + lane];
        uint r2 = rep32[(size_t)c2.x * 64 + lane];
        uint r3 = rep32[(size_t)c3.x * 64 + lane];
        uint r4 = rep32[(size_t)c4.x * 64 + lane];
        uint r5 = rep32[(size_t)c5.x * 64 + lane];
        uint r6 = rep32[(size_t)c6.x * 64 + lane];
        uint r7 = rep32[(size_t)c7.x * 64 + lane];
        ssum += a0 + a1 + a2 + a3 + a4 + a5 + a6 + a7;
        amax = fmaxf(amax, fmaxf(fmaxf(fmaxf(a0, a1), fmaxf(a2, a3)),
                                 fmaxf(fmaxf(a4, a5), fmaxf(a6, a7))));
        accx = fmaf(a0, bf2f(r0 & 0xffffu), accx);
        accy = fmaf(a0, bf2f(r0 >> 16), accy);
        accx = fmaf(a1, bf2f(r1 & 0xffffu), accx);
        accy = fmaf(a1, bf2f(r1 >> 16), accy);
        accx = fmaf(a2, bf2f(r2 & 0xffffu), accx);
        accy = fmaf(a2, bf2f(r2 >> 16), accy);
        accx = fmaf(a3, bf2f(r3 & 0xffffu), accx);
        accy = fmaf(a3, bf2f(r3 >> 16), accy);
        accx = fmaf(a4, bf2f(r4 & 0xffffu), accx);
        accy = fmaf(a4, bf2f(r4 >> 16), accy);
        accx = fmaf(a5, bf2f(r5 & 0xffffu), accx);
        accy = fmaf(a5, bf2f(r5 >> 16), accy);
        accx = fmaf(a6, bf2f(r6 & 0xffffu), accx);
        accy = fmaf(a6, bf2f(r6 >> 16), accy);
        accx = fmaf(a7, bf2f(r7 & 0xffffu), accx);
        accy = fmaf(a7, bf2f(r7 >> 16), accy);
    }
    for (; s < s1; ++s) {
        int4 c = csr[s];
        float a = __int_as_float(aoff == 1 ? c.y : c.z);
        uint r = rep32[(size_t)c.x * 64 + lane];
        ssum += a;
        amax = fmaxf(amax, a);
        accx = fmaf(a, bf2f(r & 0xffffu), accx);
        accy = fmaf(a, bf2f(r >> 16), accy);
    }
    float inv = (s1 > s0) ? 1.f / (ssum + amax * 1e-16f) : 0.f;
    uint m = rep32[(size_t)node * 64 + lane];
    float ox = fmaf(accx, inv, bf2f(m & 0xffffu));
    float oy = fmaf(accy, inv, bf2f(m >> 16));
    xout[(size_t)node * 64 + lane] = f2bf(ox) | (f2bf(oy) << 16);
}

// ---- input projection: rep(bf16) = attr(f32) @ W^T + b ----
__global__ __launch_bounds__(512) void k_input(const float* __restrict__ attr,
                                               const float* __restrict__ W,
                                               const float* __restrict__ b,
                                               uint* __restrict__ out32, int n) {
    __shared__ float Wt[128 * 130];  // Wt[k*130+o], pad keeps float2 8B-aligned
    __shared__ float xb[8][128];
    for (int idx = threadIdx.x; idx < 128 * 128; idx += 512) {
        int o = idx >> 7, k = idx & 127;
        Wt[k * 130 + o] = W[idx];
    }
    int wave = threadIdx.x >> 6, lane = threadIdx.x & 63;
    int node = blockIdx.x * 8 + wave;
    if (node < n) {
        float2 v = *(const float2*)&attr[(size_t)node * 128 + lane * 2];
        *(float2*)&xb[wave][lane * 2] = v;
    }
    __syncthreads();
    if (node >= n) return;
    float a0 = 0.f, a1 = 0.f;
#pragma unroll 8
    for (int k = 0; k < 128; ++k) {
        float xk = xb[wave][k];
        float2 w = *(const float2*)&Wt[k * 130 + lane * 2];
        a0 = fmaf(xk, w.x, a0);
        a1 = fmaf(xk, w.y, a1);
    }
    float2 bb = *(const float2*)&b[lane * 2];
    a0 += bb.x;
    a1 += bb.y;
    out32[(size_t)node * 64 + lane] = f2bf(a0) | (f2bf(a1) << 16);
}

// ---- MLP: rep(bf16) = LN(gelu(x(bf16) @ W^T + b)) ----
__global__ __launch_bounds__(512) void k_mlp(const uint* __restrict__ x32,
                                             const float* __restrict__ W,
                                             const float* __restrict__ b,
                                             const float* __restrict__ lw,
                                             const float* __restrict__ lb,
                                             uint* __restrict__ out32, int n) {
    __shared__ float Wt[128 * 130];
    __shared__ float xb[8][128];
    for (int idx = threadIdx.x; idx < 128 * 128; idx += 512) {
        int o = idx >> 7, k = idx & 127;
        Wt[k * 130 + o] = W[idx];
    }
    int wave = threadIdx.x >> 6, lane = threadIdx.x & 63;
    int node = blockIdx.x * 8 + wave;
    if (node < n) {
        uint v = x32[(size_t)node * 64 + lane];
        xb[wave][lane * 2] = bf2f(v & 0xffffu);
        xb[wave][lane * 2 + 1] = bf2f(v >> 16);
    }
    __syncthreads();
    if (node >= n) return;
    float a0 = 0.f, a1 = 0.f;
#pragma unroll 8
    for (int k = 0; k < 128; ++k) {
        float xk = xb[wave][k];
        float2 w = *(const float2*)&Wt[k * 130 + lane * 2];
        a0 = fmaf(xk, w.x, a0);
        a1 = fmaf(xk, w.y, a1);
    }
    float2 bb = *(const float2*)&b[lane * 2];
    a0 += bb.x;
    a1 += bb.y;
    float g0 = 0.5f * a0 * (1.f + erff(a0 * 0.70710678118654752f));
    float g1 = 0.5f * a1 * (1.f + erff(a1 * 0.70710678118654752f));
    float sv = g0 + g1;
#pragma unroll
    for (int m = 1; m < WAVE; m <<= 1) sv += __shfl_xor(sv, m);
    float mu = sv * (1.f / 128.f);
    float d0 = g0 - mu, d1 = g1 - mu;
    float vv = d0 * d0 + d1 * d1;
#pragma unroll
    for (int m = 1; m < WAVE; m <<= 1) vv += __shfl_xor(vv, m);
    float rstd = rsqrtf(vv * (1.f / 128.f) + 1e-5f);
    float2 w2 = *(const float2*)&lw[lane * 2];
    float2 b2 = *(const float2*)&lb[lane * 2];
    float o0 = d0 * rstd * w2.x + b2.x;
    float o1 = d1 * rstd * w2.y + b2.y;
    out32[(size_t)node * 64 + lane] = f2bf(o0) | (f2bf(o1) << 16);
}

// ---- output projection: out(f32) = rep(bf16) @ W_out^T + b_out (64 outs) ----
__global__ __launch_bounds__(512) void k_out(const uint* __restrict__ rep32,
                                             const float* __restrict__ W,
                                             const float* __restrict__ b,
                                             float* __restrict__ out, int n) {
    __shared__ float Wt[128 * 65];  // Wt[k*65+o]
    __shared__ float xb[8][128];
    for (int idx = threadIdx.x; idx < 64 * 128; idx += 512) {
        int o = idx >> 7, k = idx & 127;
        Wt[k * 65 + o] = W[idx];
    }
    int wave = threadIdx.x >> 6, lane = threadIdx.x & 63;
    int node = blockIdx.x * 8 + wave;
    if (node < n) {
        uint v = rep32[(size_t)node * 64 + lane];
        xb[wave][lane * 2] = bf2f(v & 0xffffu);
        xb[wave][lane * 2 + 1] = bf2f(v >> 16);
    }
    __syncthreads();
    if (node >= n) return;
    float acc = 0.f;
#pragma unroll 8
    for (int k = 0; k < 128; ++k) acc = fmaf(xb[wave][k], Wt[k * 65 + lane], acc);
    out[(size_t)node * 64 + lane] = acc + b[lane];
}

extern "C" void kernel_launch(void* const* d_in, const int* in_sizes, int n_in,
                              void* d_out, int out_size, void* d_ws, size_t ws_size,
                              hipStream_t stream) {
    const float* node_attr = (const float*)d_in[0];
    const int* ei = (const int*)d_in[1];
    // d_in[2] = batch_idx (unused)
    const float* adv = (const float*)d_in[3];
    const float* W_inp = (const float*)d_in[4];
    const float* b_inp = (const float*)d_in[5];
    const float* W_a = (const float*)d_in[6];
    const float* b_a = (const float*)d_in[7];
    const float* ln_w = (const float*)d_in[8];
    const float* ln_b = (const float*)d_in[9];
    const float* W_out = (const float*)d_in[10];
    const float* b_out = (const float*)d_in[11];

    const int n = in_sizes[0] / 128;
    const int E = in_sizes[1] / 2;

    // workspace: A, B (bf16x2 packed, n*64 dwords), csr (E int4), scan temps
    uint* A = (uint*)d_ws;
    uint* B = A + (size_t)n * 64;
    int4* csr = (int4*)(B + (size_t)n * 64);   // 16B-aligned: 2*n*256B offset
    int* deg = (int*)(csr + E);
    int* cursor = deg + n;
    int* excl = cursor + n;
    int* row_ptr = excl + n;      // n+1
    int* bsum = row_ptr + n + 1;  // 256

    const int* src = ei;
    const int* dst = ei + E;

    hipMemsetAsync(deg, 0, (size_t)n * sizeof(int), stream);

    int eb = (E + 255) / 256;
    int nbs = (n + 255) / 256;  // n <= 65536 supported by k_scan2
    k_count<<<eb, 256, 0, stream>>>(dst, E, deg);
    k_scan1<<<nbs, 256, 0, stream>>>(deg, n, excl, bsum);
    k_scan2<<<1, 256, 0, stream>>>(bsum, nbs);
    k_scan3<<<nbs, 256, 0, stream>>>(deg, excl, bsum, n, row_ptr, cursor);
    int sb = 8 * ((E + SCHUNK - 1) / SCHUNK);
    k_scatter<<<sb, 256, 0, stream>>>(src, dst, adv, E, n, cursor, csr);

    int nb8 = (n + 7) / 8;
    k_input<<<nb8, 512, 0, stream>>>(node_attr, W_inp, b_inp, A, n);

    // layer 0: B = aggr(A); A = mlp(B)
    k_aggr<<<nb8, 512, 0, stream>>>(A, row_ptr, csr, 1, B, n);
    k_mlp<<<nb8, 512, 0, stream>>>(B, W_a, b_a, ln_w, ln_b, A, n);
    // layer 1: B = aggr(A); A = mlp(B)
    k_aggr<<<nb8, 512, 0, stream>>>(A, row_ptr, csr, 2, B, n);
    k_mlp<<<nb8, 512, 0, stream>>>(B, W_a + 128 * 128, b_a + 128,
                                   ln_w + 128, ln_b + 128, A, n);

    k_out<<<nb8, 512, 0, stream>>>(A, W_out, b_out, (float*)d_out, n);
}

// Round 6
// 381.980 us; speedup vs baseline: 4.1390x; 1.5946x over previous
//
#include <hip/hip_runtime.h>
#include <hip/hip_bf16.h>
#include <math.h>

// ---------------------------------------------------------------------------
// GNN: rep = attr @ W_inp^T + b
//      2x { x = (segsoftmax-weighted aggr of rep[src] by dst) + rep;
//           rep = LN(gelu(x @ W_a^T + b)) }
//      out = rep @ W_out^T + b_out
// segment_softmax(log a) == a / (ssum + amax*1e-16) -> per-node scalar.
// CSR by dst rebuilt per call (count -> 3-phase scan -> XCD-partitioned
// scatter). Node features packed bf16x2. Dense layers use bf16 MFMA
// (16x16x32): W staged f32->bf16 in LDS (row pad +8 shorts => conflict-free
// ds_read_b128 B-frags), per-wave 32 nodes x 128 outs, GELU+LN fused in the
// epilogue via 16-lane shfl reductions.
// ---------------------------------------------------------------------------

#define WAVE 64

typedef __attribute__((ext_vector_type(8))) short bf16x8;
typedef __attribute__((ext_vector_type(4))) float f32x4;
union ABu { uint4 u; bf16x8 v; };
union ABh { ushort h[8]; bf16x8 v; };

static __device__ __forceinline__ float bf2f(uint u16) {
    union { uint i; float f; } c;
    c.i = u16 << 16;
    return c.f;
}
static __device__ __forceinline__ uint f2bf(float f) {
    uint x = __float_as_uint(f);
    return (x + 0x7FFFu + ((x >> 16) & 1u)) >> 16;  // RNE
}

__global__ void k_count(const int* __restrict__ dst, int E, int* __restrict__ deg) {
    int e = blockIdx.x * blockDim.x + threadIdx.x;
    if (e < E) atomicAdd(&deg[dst[e]], 1);
}

// ---- 3-phase scan over deg[n] (n <= 256*256) ----
__global__ __launch_bounds__(256) void k_scan1(const int* __restrict__ deg, int n,
                                               int* __restrict__ excl,
                                               int* __restrict__ bsum) {
    __shared__ int sd[256];
    int t = threadIdx.x, i = blockIdx.x * 256 + t;
    int v = (i < n) ? deg[i] : 0;
    sd[t] = v;
    __syncthreads();
    for (int off = 1; off < 256; off <<= 1) {
        int u = (t >= off) ? sd[t - off] : 0;
        __syncthreads();
        sd[t] += u;
        __syncthreads();
    }
    if (i < n) excl[i] = sd[t] - v;
    if (t == 255) bsum[blockIdx.x] = sd[255];
}

__global__ __launch_bounds__(256) void k_scan2(int* __restrict__ bsum, int nb) {
    __shared__ int sd[256];
    int t = threadIdx.x;
    int v = (t < nb) ? bsum[t] : 0;
    sd[t] = v;
    __syncthreads();
    for (int off = 1; off < 256; off <<= 1) {
        int u = (t >= off) ? sd[t - off] : 0;
        __syncthreads();
        sd[t] += u;
        __syncthreads();
    }
    if (t < nb) bsum[t] = sd[t] - v;  // exclusive block offsets
}

__global__ __launch_bounds__(256) void k_scan3(const int* __restrict__ deg,
                                               const int* __restrict__ excl,
                                               const int* __restrict__ bsum, int n,
                                               int* __restrict__ row_ptr,
                                               int* __restrict__ cursor) {
    int i = blockIdx.x * 256 + threadIdx.x;
    if (i < n) {
        int rp = bsum[blockIdx.x] + excl[i];
        row_ptr[i] = rp;
        cursor[i] = rp;
        if (i == n - 1) row_ptr[n] = rp + deg[i];
    }
}

// ---- scatter: XCD-partitioned (blockIdx&7 -> dst range) ----
#define SCHUNK 4096
__global__ __launch_bounds__(256) void k_scatter(const int* __restrict__ src,
                                                 const int* __restrict__ dst,
                                                 const float* __restrict__ adv, int E,
                                                 int n, int* __restrict__ cursor,
                                                 int4* __restrict__ csr) {
    int part = blockIdx.x & 7;
    int chunk = blockIdx.x >> 3;
    int PART = (n + 7) >> 3;
    int lo = part * PART, hi = lo + PART;
    int base = chunk * SCHUNK + threadIdx.x;
#pragma unroll
    for (int i = 0; i < SCHUNK / 256; ++i) {
        int e = base + i * 256;
        if (e < E) {
            int d = dst[e];
            if (d >= lo && d < hi) {
                int p = atomicAdd(&cursor[d], 1);
                csr[p] = make_int4(src[e], __float_as_int(adv[e]),
                                   __float_as_int(adv[E + e]), 0);
            }
        }
    }
}

// ---- aggregation: one wave per node, single pass; rep packed bf16x2 ----
__global__ __launch_bounds__(512) void k_aggr(const uint* __restrict__ rep32,
                                              const int* __restrict__ row_ptr,
                                              const int4* __restrict__ csr, int aoff,
                                              uint* __restrict__ xout, int n) {
    int wave = threadIdx.x >> 6, lane = threadIdx.x & 63;
    int node = blockIdx.x * 8 + wave;
    if (node >= n) return;
    int s0 = row_ptr[node], s1 = row_ptr[node + 1];
    float accx = 0.f, accy = 0.f, ssum = 0.f, amax = 0.f;
    int s = s0;
    for (; s + 8 <= s1; s += 8) {
        int4 c0 = csr[s], c1 = csr[s + 1], c2 = csr[s + 2], c3 = csr[s + 3];
        int4 c4 = csr[s + 4], c5 = csr[s + 5], c6 = csr[s + 6], c7 = csr[s + 7];
        float a0 = __int_as_float(aoff == 1 ? c0.y : c0.z);
        float a1 = __int_as_float(aoff == 1 ? c1.y : c1.z);
        float a2 = __int_as_float(aoff == 1 ? c2.y : c2.z);
        float a3 = __int_as_float(aoff == 1 ? c3.y : c3.z);
        float a4 = __int_as_float(aoff == 1 ? c4.y : c4.z);
        float a5 = __int_as_float(aoff == 1 ? c5.y : c5.z);
        float a6 = __int_as_float(aoff == 1 ? c6.y : c6.z);
        float a7 = __int_as_float(aoff == 1 ? c7.y : c7.z);
        uint r0 = rep32[(size_t)c0.x * 64 + lane];
        uint r1 = rep32[(size_t)c1.x * 64 + lane];
        uint r2 = rep32[(size_t)c2.x * 64 + lane];
        uint r3 = rep32[(size_t)c3.x * 64 + lane];
        uint r4 = rep32[(size_t)c4.x * 64 + lane];
        uint r5 = rep32[(size_t)c5.x * 64 + lane];
        uint r6 = rep32[(size_t)c6.x * 64 + lane];
        uint r7 = rep32[(size_t)c7.x * 64 + lane];
        ssum += a0 + a1 + a2 + a3 + a4 + a5 + a6 + a7;
        amax = fmaxf(amax, fmaxf(fmaxf(fmaxf(a0, a1), fmaxf(a2, a3)),
                                 fmaxf(fmaxf(a4, a5), fmaxf(a6, a7))));
        accx = fmaf(a0, bf2f(r0 & 0xffffu), accx);
        accy = fmaf(a0, bf2f(r0 >> 16), accy);
        accx = fmaf(a1, bf2f(r1 & 0xffffu), accx);
        accy = fmaf(a1, bf2f(r1 >> 16), accy);
        accx = fmaf(a2, bf2f(r2 & 0xffffu), accx);
        accy = fmaf(a2, bf2f(r2 >> 16), accy);
        accx = fmaf(a3, bf2f(r3 & 0xffffu), accx);
        accy = fmaf(a3, bf2f(r3 >> 16), accy);
        accx = fmaf(a4, bf2f(r4 & 0xffffu), accx);
        accy = fmaf(a4, bf2f(r4 >> 16), accy);
        accx = fmaf(a5, bf2f(r5 & 0xffffu), accx);
        accy = fmaf(a5, bf2f(r5 >> 16), accy);
        accx = fmaf(a6, bf2f(r6 & 0xffffu), accx);
        accy = fmaf(a6, bf2f(r6 >> 16), accy);
        accx = fmaf(a7, bf2f(r7 & 0xffffu), accx);
        accy = fmaf(a7, bf2f(r7 >> 16), accy);
    }
    for (; s < s1; ++s) {
        int4 c = csr[s];
        float a = __int_as_float(aoff == 1 ? c.y : c.z);
        uint r = rep32[(size_t)c.x * 64 + lane];
        ssum += a;
        amax = fmaxf(amax, a);
        accx = fmaf(a, bf2f(r & 0xffffu), accx);
        accy = fmaf(a, bf2f(r >> 16), accy);
    }
    float inv = (s1 > s0) ? 1.f / (ssum + amax * 1e-16f) : 0.f;
    uint m = rep32[(size_t)node * 64 + lane];
    float ox = fmaf(accx, inv, bf2f(m & 0xffffu));
    float oy = fmaf(accy, inv, bf2f(m >> 16));
    xout[(size_t)node * 64 + lane] = f2bf(ox) | (f2bf(oy) << 16);
}

// ============================ dense MFMA kernels ============================
// 512 threads = 8 waves; wave handles 32 nodes (2 row-tiles of 16).
// A-frag: lane holds x[row = base + (l&15)][k = kb*32 + (l>>4)*8 + j].
// B-frag: lane holds W[col = ct*16 + (l&15)][k = kb*32 + (l>>4)*8 + j] from LDS.
// D: col = l&15, row(in tile) = (l>>4)*4 + i.
#define WROW 136  // shorts per LDS W row (128 + 8 pad -> 2-way banks = free)

// ---- MLP: rep(bf16) = LN(gelu(x(bf16) @ W^T + b)) ----
__global__ __launch_bounds__(512) void k_mlp(const uint* __restrict__ x32,
                                             const float* __restrict__ W,
                                             const float* __restrict__ b,
                                             const float* __restrict__ lw,
                                             const float* __restrict__ lb,
                                             uint* __restrict__ out32, int n) {
    __shared__ ushort Wbf[128 * WROW];
    uint* wd = (uint*)Wbf;
    for (int idx = threadIdx.x; idx < 128 * 64; idx += 512) {
        int row = idx >> 6, d = idx & 63;
        float2 w2 = *(const float2*)&W[row * 128 + d * 2];
        wd[row * (WROW / 2) + d] = f2bf(w2.x) | (f2bf(w2.y) << 16);
    }
    __syncthreads();
    int wv = threadIdx.x >> 6, l = threadIdx.x & 63;
    int c = l & 15, q = l >> 4;
    int base = blockIdx.x * 256 + wv * 32;
    int r0 = min(base + c, n - 1);
    int r1 = min(base + 16 + c, n - 1);

    f32x4 acc[2][8];
#pragma unroll
    for (int rt = 0; rt < 2; ++rt)
#pragma unroll
        for (int ct = 0; ct < 8; ++ct) acc[rt][ct] = (f32x4){0.f, 0.f, 0.f, 0.f};

#pragma unroll
    for (int kb = 0; kb < 4; ++kb) {
        ABu a0, a1;
        a0.u = *(const uint4*)&x32[(size_t)r0 * 64 + kb * 16 + q * 4];
        a1.u = *(const uint4*)&x32[(size_t)r1 * 64 + kb * 16 + q * 4];
#pragma unroll
        for (int ct = 0; ct < 8; ++ct) {
            bf16x8 bf = *(const bf16x8*)&Wbf[(ct * 16 + c) * WROW + kb * 32 + q * 8];
            acc[0][ct] = __builtin_amdgcn_mfma_f32_16x16x32_bf16(a0.v, bf, acc[0][ct], 0, 0, 0);
            acc[1][ct] = __builtin_amdgcn_mfma_f32_16x16x32_bf16(a1.v, bf, acc[1][ct], 0, 0, 0);
        }
    }

    float bias[8], lwv[8], lbv[8];
#pragma unroll
    for (int ct = 0; ct < 8; ++ct) {
        bias[ct] = b[ct * 16 + c];
        lwv[ct] = lw[ct * 16 + c];
        lbv[ct] = lb[ct * 16 + c];
    }

#pragma unroll
    for (int rt = 0; rt < 2; ++rt) {
        // bias + gelu in place
#pragma unroll
        for (int ct = 0; ct < 8; ++ct)
#pragma unroll
            for (int i = 0; i < 4; ++i) {
                float h = acc[rt][ct][i] + bias[ct];
                acc[rt][ct][i] = 0.5f * h * (1.f + erff(h * 0.70710678118654752f));
            }
        // layernorm over 128 cols (8 ct here x 16 lanes in group)
        float mu[4], rstd[4];
#pragma unroll
        for (int i = 0; i < 4; ++i) {
            float s = 0.f;
#pragma unroll
            for (int ct = 0; ct < 8; ++ct) s += acc[rt][ct][i];
            s += __shfl_xor(s, 1);
            s += __shfl_xor(s, 2);
            s += __shfl_xor(s, 4);
            s += __shfl_xor(s, 8);
            mu[i] = s * (1.f / 128.f);
        }
#pragma unroll
        for (int i = 0; i < 4; ++i) {
            float v = 0.f;
#pragma unroll
            for (int ct = 0; ct < 8; ++ct) {
                float d = acc[rt][ct][i] - mu[i];
                v += d * d;
            }
            v += __shfl_xor(v, 1);
            v += __shfl_xor(v, 2);
            v += __shfl_xor(v, 4);
            v += __shfl_xor(v, 8);
            rstd[i] = rsqrtf(v * (1.f / 128.f) + 1e-5f);
        }
        // normalize, pack bf16x2 via lane-pair exchange, store (even-c lanes)
#pragma unroll
        for (int ct = 0; ct < 8; ++ct)
#pragma unroll
            for (int i = 0; i < 4; ++i) {
                float o = (acc[rt][ct][i] - mu[i]) * rstd[i] * lwv[ct] + lbv[ct];
                float p = __shfl_xor(o, 1);
                uint dw = (c & 1) ? (f2bf(p) | (f2bf(o) << 16))
                                  : (f2bf(o) | (f2bf(p) << 16));
                int R = base + rt * 16 + q * 4 + i;
                if (R < n && (c & 1) == 0)
                    out32[(size_t)R * 64 + ct * 8 + (c >> 1)] = dw;
            }
    }
}

// ---- input projection: rep(bf16) = attr(f32) @ W^T + b ----
__global__ __launch_bounds__(512) void k_input(const float* __restrict__ attr,
                                               const float* __restrict__ W,
                                               const float* __restrict__ b,
                                               uint* __restrict__ out32, int n) {
    __shared__ ushort Wbf[128 * WROW];
    uint* wd = (uint*)Wbf;
    for (int idx = threadIdx.x; idx < 128 * 64; idx += 512) {
        int row = idx >> 6, d = idx & 63;
        float2 w2 = *(const float2*)&W[row * 128 + d * 2];
        wd[row * (WROW / 2) + d] = f2bf(w2.x) | (f2bf(w2.y) << 16);
    }
    __syncthreads();
    int wv = threadIdx.x >> 6, l = threadIdx.x & 63;
    int c = l & 15, q = l >> 4;
    int base = blockIdx.x * 256 + wv * 32;
    int r0 = min(base + c, n - 1);
    int r1 = min(base + 16 + c, n - 1);

    f32x4 acc[2][8];
#pragma unroll
    for (int rt = 0; rt < 2; ++rt)
#pragma unroll
        for (int ct = 0; ct < 8; ++ct) acc[rt][ct] = (f32x4){0.f, 0.f, 0.f, 0.f};

#pragma unroll
    for (int kb = 0; kb < 4; ++kb) {
        ABh a0, a1;
        float4 f0 = *(const float4*)&attr[(size_t)r0 * 128 + kb * 32 + q * 8];
        float4 f1 = *(const float4*)&attr[(size_t)r0 * 128 + kb * 32 + q * 8 + 4];
        a0.h[0] = f2bf(f0.x); a0.h[1] = f2bf(f0.y); a0.h[2] = f2bf(f0.z); a0.h[3] = f2bf(f0.w);
        a0.h[4] = f2bf(f1.x); a0.h[5] = f2bf(f1.y); a0.h[6] = f2bf(f1.z); a0.h[7] = f2bf(f1.w);
        float4 g0 = *(const float4*)&attr[(size_t)r1 * 128 + kb * 32 + q * 8];
        float4 g1 = *(const float4*)&attr[(size_t)r1 * 128 + kb * 32 + q * 8 + 4];
        a1.h[0] = f2bf(g0.x); a1.h[1] = f2bf(g0.y); a1.h[2] = f2bf(g0.z); a1.h[3] = f2bf(g0.w);
        a1.h[4] = f2bf(g1.x); a1.h[5] = f2bf(g1.y); a1.h[6] = f2bf(g1.z); a1.h[7] = f2bf(g1.w);
#pragma unroll
        for (int ct = 0; ct < 8; ++ct) {
            bf16x8 bf = *(const bf16x8*)&Wbf[(ct * 16 + c) * WROW + kb * 32 + q * 8];
            acc[0][ct] = __builtin_amdgcn_mfma_f32_16x16x32_bf16(a0.v, bf, acc[0][ct], 0, 0, 0);
            acc[1][ct] = __builtin_amdgcn_mfma_f32_16x16x32_bf16(a1.v, bf, acc[1][ct], 0, 0, 0);
        }
    }
    float bias[8];
#pragma unroll
    for (int ct = 0; ct < 8; ++ct) bias[ct] = b[ct * 16 + c];
#pragma unroll
    for (int rt = 0; rt < 2; ++rt)
#pragma unroll
        for (int ct = 0; ct < 8; ++ct)
#pragma unroll
            for (int i = 0; i < 4; ++i) {
                float o = acc[rt][ct][i] + bias[ct];
                float p = __shfl_xor(o, 1);
                uint dw = (c & 1) ? (f2bf(p) | (f2bf(o) << 16))
                                  : (f2bf(o) | (f2bf(p) << 16));
                int R = base + rt * 16 + q * 4 + i;
                if (R < n && (c & 1) == 0)
                    out32[(size_t)R * 64 + ct * 8 + (c >> 1)] = dw;
            }
}

// ---- output projection: out(f32) = rep(bf16) @ W_out^T + b_out (64 outs) ----
__global__ __launch_bounds__(512) void k_out(const uint* __restrict__ rep32,
                                             const float* __restrict__ W,
                                             const float* __restrict__ b,
                                             float* __restrict__ out, int n) {
    __shared__ ushort Wbf[64 * WROW];
    uint* wd = (uint*)Wbf;
    for (int idx = threadIdx.x; idx < 64 * 64; idx += 512) {
        int row = idx >> 6, d = idx & 63;
        float2 w2 = *(const float2*)&W[row * 128 + d * 2];
        wd[row * (WROW / 2) + d] = f2bf(w2.x) | (f2bf(w2.y) << 16);
    }
    __syncthreads();
    int wv = threadIdx.x >> 6, l = threadIdx.x & 63;
    int c = l & 15, q = l >> 4;
    int base = blockIdx.x * 256 + wv * 32;
    int r0 = min(base + c, n - 1);
    int r1 = min(base + 16 + c, n - 1);

    f32x4 acc[2][4];
#pragma unroll
    for (int rt = 0; rt < 2; ++rt)
#pragma unroll
        for (int ct = 0; ct < 4; ++ct) acc[rt][ct] = (f32x4){0.f, 0.f, 0.f, 0.f};

#pragma unroll
    for (int kb = 0; kb < 4; ++kb) {
        ABu a0, a1;
        a0.u = *(const uint4*)&rep32[(size_t)r0 * 64 + kb * 16 + q * 4];
        a1.u = *(const uint4*)&rep32[(size_t)r1 * 64 + kb * 16 + q * 4];
#pragma unroll
        for (int ct = 0; ct < 4; ++ct) {
            bf16x8 bf = *(const bf16x8*)&Wbf[(ct * 16 + c) * WROW + kb * 32 + q * 8];
            acc[0][ct] = __builtin_amdgcn_mfma_f32_16x16x32_bf16(a0.v, bf, acc[0][ct], 0, 0, 0);
            acc[1][ct] = __builtin_amdgcn_mfma_f32_16x16x32_bf16(a1.v, bf, acc[1][ct], 0, 0, 0);
        }
    }
    float bias[4];
#pragma unroll
    for (int ct = 0; ct < 4; ++ct) bias[ct] = b[ct * 16 + c];
#pragma unroll
    for (int rt = 0; rt < 2; ++rt)
#pragma unroll
        for (int ct = 0; ct < 4; ++ct)
#pragma unroll
            for (int i = 0; i < 4; ++i) {
                int R = base + rt * 16 + q * 4 + i;
                if (R < n) out[(size_t)R * 64 + ct * 16 + c] = acc[rt][ct][i] + bias[ct];
            }
}

extern "C" void kernel_launch(void* const* d_in, const int* in_sizes, int n_in,
                              void* d_out, int out_size, void* d_ws, size_t ws_size,
                              hipStream_t stream) {
    const float* node_attr = (const float*)d_in[0];
    const int* ei = (const int*)d_in[1];
    // d_in[2] = batch_idx (unused)
    const float* adv = (const float*)d_in[3];
    const float* W_inp = (const float*)d_in[4];
    const float* b_inp = (const float*)d_in[5];
    const float* W_a = (const float*)d_in[6];
    const float* b_a = (const float*)d_in[7];
    const float* ln_w = (const float*)d_in[8];
    const float* ln_b = (const float*)d_in[9];
    const float* W_out = (const float*)d_in[10];
    const float* b_out = (const float*)d_in[11];

    const int n = in_sizes[0] / 128;
    const int E = in_sizes[1] / 2;

    // workspace: A, B (bf16x2 packed, n*64 dwords), csr (E int4), scan temps
    uint* A = (uint*)d_ws;
    uint* B = A + (size_t)n * 64;
    int4* csr = (int4*)(B + (size_t)n * 64);
    int* deg = (int*)(csr + E);
    int* cursor = deg + n;
    int* excl = cursor + n;
    int* row_ptr = excl + n;      // n+1
    int* bsum = row_ptr + n + 1;  // 256

    const int* src = ei;
    const int* dst = ei + E;

    hipMemsetAsync(deg, 0, (size_t)n * sizeof(int), stream);

    int eb = (E + 255) / 256;
    int nbs = (n + 255) / 256;
    k_count<<<eb, 256, 0, stream>>>(dst, E, deg);
    k_scan1<<<nbs, 256, 0, stream>>>(deg, n, excl, bsum);
    k_scan2<<<1, 256, 0, stream>>>(bsum, nbs);
    k_scan3<<<nbs, 256, 0, stream>>>(deg, excl, bsum, n, row_ptr, cursor);
    int sb = 8 * ((E + SCHUNK - 1) / SCHUNK);
    k_scatter<<<sb, 256, 0, stream>>>(src, dst, adv, E, n, cursor, csr);

    int nbd = (n + 255) / 256;  // dense kernels: 256 nodes/block
    int nb8 = (n + 7) / 8;
    k_input<<<nbd, 512, 0, stream>>>(node_attr, W_inp, b_inp, A, n);

    // layer 0: B = aggr(A); A = mlp(B)
    k_aggr<<<nb8, 512, 0, stream>>>(A, row_ptr, csr, 1, B, n);
    k_mlp<<<nbd, 512, 0, stream>>>(B, W_a, b_a, ln_w, ln_b, A, n);
    // layer 1: B = aggr(A); A = mlp(B)
    k_aggr<<<nb8, 512, 0, stream>>>(A, row_ptr, csr, 2, B, n);
    k_mlp<<<nbd, 512, 0, stream>>>(B, W_a + 128 * 128, b_a + 128,
                                   ln_w + 128, ln_b + 128, A, n);

    k_out<<<nbd, 512, 0, stream>>>(A, W_out, b_out, (float*)d_out, n);
}